// Round 9
// baseline (3063.025 us; speedup 1.0000x reference)
//
#include <hip/hip_runtime.h>
#include <stdint.h>

typedef __bf16 bf16x8_t __attribute__((ext_vector_type(8)));
typedef float  f32x4_t  __attribute__((ext_vector_type(4)));

#define MFMA_BF16(A, Bv, C) __builtin_amdgcn_mfma_f32_16x16x32_bf16((A), (Bv), (C), 0, 0, 0)

static constexpr int BB = 16;      // batch
static constexpr int LL = 1024;    // seq len
static constexpr int DD = 2048;    // input dim
static constexpr int HH = 512;     // hidden
static constexpr int GG = 4 * HH;  // 2048 gate rows
static constexpr int MM = BB * LL; // 16384

// ---- workspace layout (bytes) ----
static constexpr size_t XBF_OFF   = 0;                                    // x bf16 [MM][DD]
static constexpr size_t WIHBF_OFF = XBF_OFF   + (size_t)MM * DD * 2;      // W_ih bf16 [GG][DD]
static constexpr size_t WHHBF_OFF = WIHBF_OFF + (size_t)GG * DD * 2;      // W_hh bf16 [GG][HH]
static constexpr size_t XGBF_OFF  = WHHBF_OFF + (size_t)GG * HH * 2;      // xg bf16 [MM][GG]
static constexpr size_t GARR_OFF  = XGBF_OFF  + (size_t)MM * GG * 2;      // g f32 [MM]
static constexpr size_t PART_OFF  = GARR_OFF  + (size_t)MM * 4;           // partials f32 [BB][8][HH]
static constexpr size_t TBUF_OFF  = PART_OFF  + (size_t)BB * 8 * HH * 4;  // tagged h u32 [2][BB][HH]
static constexpr size_t TABL_OFF  = TBUF_OFF  + (size_t)2 * BB * HH * 4;  // XCD table u32 [256]
static constexpr size_t WS_NEED   = TABL_OFF  + 256 * 4;                  // ~145.2 MB

__device__ __forceinline__ unsigned short f2bf(float f) {
  union { float f; uint32_t u; } v; v.f = f;
  uint32_t r = v.u + 0x7FFFu + ((v.u >> 16) & 1u);   // RNE
  return (unsigned short)(r >> 16);
}
__device__ __forceinline__ float bf2f(unsigned short s) {
  union { uint32_t u; float f; } v; v.u = ((uint32_t)s) << 16;
  return v.f;
}
__device__ __forceinline__ float sigmoidf_fast(float x) { return 1.f / (1.f + __expf(-x)); }
__device__ __forceinline__ float tanhf_fast(float x) {
  float ax = fabsf(x);
  float e  = __expf(2.f * ax);
  float t  = 1.f - 2.f / (e + 1.f);
  return copysignf(t, x);
}
__device__ __forceinline__ void async_cp16(const void* g, void* lds) {
  __builtin_amdgcn_global_load_lds((const __attribute__((address_space(1))) uint32_t*)g,
                                   (__attribute__((address_space(3))) uint32_t*)lds, 16, 0, 0);
}

// ---------------- fp32 -> bf16 convert (vectorized) ----------------
__global__ __launch_bounds__(256) void k_f32_to_bf16(const float* __restrict__ s,
                                                     unsigned short* __restrict__ d, int n4) {
  int i = blockIdx.x * 256 + threadIdx.x;
  int stride = gridDim.x * 256;
  for (; i < n4; i += stride) {
    float4 v = ((const float4*)s)[i];
    ushort4 o;
    o.x = f2bf(v.x); o.y = f2bf(v.y); o.z = f2bf(v.z); o.w = f2bf(v.w);
    ((ushort4*)d)[i] = o;
  }
}

// ---------------- xg = x @ W_ih^T + (b_ih + b_hh), bf16 MFMA ----------------
__global__ __launch_bounds__(256) void k_gemm_xg(const unsigned short* __restrict__ A,
                                                 const unsigned short* __restrict__ Bw,
                                                 const float* __restrict__ b_ih,
                                                 const float* __restrict__ b_hh,
                                                 unsigned short* __restrict__ C) {
  __shared__ __align__(16) unsigned short As[128 * 32];
  __shared__ __align__(16) unsigned short Bs[128 * 32];
  const int bid = blockIdx.x;
  const int bn = bid & 15, bm = bid >> 4;
  const int row0 = bm * 128, col0 = bn * 128;
  const int tid = threadIdx.x;
  const int lane = tid & 63, w = tid >> 6;
  const int wr = w >> 1, wc = w & 1;
  const int l15 = lane & 15, l4 = lane >> 4;

  const f32x4_t z4 = {0.f, 0.f, 0.f, 0.f};
  f32x4_t acc[4][4];
#pragma unroll
  for (int mi = 0; mi < 4; ++mi)
#pragma unroll
    for (int ni = 0; ni < 4; ++ni) acc[mi][ni] = z4;

  const unsigned short* ga = A  + (size_t)(row0 + (tid >> 2)) * DD + (tid & 3) * 8;
  const unsigned short* gb = Bw + (size_t)(col0 + (tid >> 2)) * DD + (tid & 3) * 8;
  unsigned short* asw = As + w * 512;
  unsigned short* bsw = Bs + w * 512;

  for (int k0 = 0; k0 < DD; k0 += 32) {
    async_cp16(ga + k0,           asw);
    async_cp16(ga + k0 + 64 * DD, asw + 2048);
    async_cp16(gb + k0,           bsw);
    async_cp16(gb + k0 + 64 * DD, bsw + 2048);
    __syncthreads();
    bf16x8_t af[4], bfr[4];
#pragma unroll
    for (int mi = 0; mi < 4; ++mi)
      af[mi] = *(const bf16x8_t*)(As + (wr * 64 + mi * 16 + l15) * 32 + l4 * 8);
#pragma unroll
    for (int ni = 0; ni < 4; ++ni)
      bfr[ni] = *(const bf16x8_t*)(Bs + (wc * 64 + ni * 16 + l15) * 32 + l4 * 8);
#pragma unroll
    for (int mi = 0; mi < 4; ++mi)
#pragma unroll
      for (int ni = 0; ni < 4; ++ni)
        acc[mi][ni] = MFMA_BF16(af[mi], bfr[ni], acc[mi][ni]);
    __syncthreads();
  }
#pragma unroll
  for (int ni = 0; ni < 4; ++ni) {
    int col = col0 + wc * 64 + ni * 16 + l15;
    float bias = b_ih[col] + b_hh[col];
#pragma unroll
    for (int mi = 0; mi < 4; ++mi) {
      int rowb = row0 + wr * 64 + mi * 16 + l4 * 4;
#pragma unroll
      for (int r = 0; r < 4; ++r)
        C[(size_t)(rowb + r) * GG + col] = f2bf(acc[mi][ni][r] + bias);
    }
  }
}

// ---------------- LSTM recurrence ----------------
// R6 structure + two serialization fixes:
// (1) wave role separation: waves 0-2 poll+stage (no stores -> poll is pure
//     load RT; vmcnt retires in issue order, so a polling wave that also
//     issued the HBM h_all store paid ~600-900cyc store-ack every step);
//     wave 3 runs the tail + all publishes and never polls.
// (2) verified XCD-local exchange: prologue registers each WG's XCC_ID in a
//     table; all WGs compute identically (syncthreads_and over the shared
//     table) whether round-robin (sel=1) or chunked (sel=2) grouping makes
//     every batch's 16 WGs XCD-local, and pick the mapping accordingly.
//     Producers dual-publish the SAME word (plain store -> local L2, agent
//     store -> MALL; identical data so any eviction order stays coherent).
//     Local consumers poll via sc0 (L2) with agent-load fallback interleaved.
__global__ __launch_bounds__(256, 1) void k_lstm(const unsigned short* __restrict__ Whh,
                                                 const unsigned short* __restrict__ xg,
                                                 float* __restrict__ h_all,
                                                 unsigned int* tbuf,
                                                 unsigned int* tabl) {
  const int bid = blockIdx.x;
  const int tid = threadIdx.x;
  const int lane = tid & 63, w = tid >> 6;    // wave w handles gate w (0=i,1=f,2=g,3=o)
  const int l15 = lane & 15, l4 = lane >> 4;

  __shared__ float gl[4][32];                 // activated gates
  __shared__ __align__(16) unsigned short h_lds[HH];
  __shared__ unsigned int s_tab[256];

  // ---- pre-pass: register XCD, detect grouping, pick mapping ----
  if (tid == 0) {
    unsigned int xcd;
    asm volatile("s_getreg_b32 %0, hwreg(HW_REG_XCC_ID)" : "=s"(xcd));
    __hip_atomic_store(tabl + bid, (xcd & 0xF) + 1u, __ATOMIC_RELAXED, __HIP_MEMORY_SCOPE_AGENT);
  }
  {
    unsigned int v = 0, guard = 0;
    for (;;) {
      v = __hip_atomic_load(tabl + tid, __ATOMIC_RELAXED, __HIP_MEMORY_SCOPE_AGENT);
      if (v != 0) break;
      if (++guard > (1u << 18)) break;   // failsafe
    }
    s_tab[tid] = v;
  }
  __syncthreads();
  const int rr_ok = __syncthreads_and((int)(s_tab[tid] == s_tab[(tid & 7) | (tid & 128)]));
  const int ch_ok = __syncthreads_and((int)(s_tab[tid] == s_tab[tid & ~15]));
  const int sel = rr_ok ? 1 : (ch_ok ? 2 : 0);
  const bool mode_local = (sel != 0);

  int b, wg;
  if (sel == 2) { b = bid >> 4;                     wg = bid & 15; }
  else          { b = (bid & 7) + 8 * (bid >> 7);   wg = (bid >> 3) & 15; }
  const int K0 = wg * 32;

  // ---- bootstrap: dual-publish tag0 (h[-1]=0) for own slots, both parities ----
  if (tid >= 192 && tid < 224) {
    const int e = tid - 192;
#pragma unroll
    for (int p = 0; p < 2; ++p) {
      unsigned int* dst = tbuf + ((p * BB + b) << 9) + K0 + e;
      *(volatile unsigned int*)dst = 0u;
      __hip_atomic_store(dst, 0u, __ATOMIC_RELAXED, __HIP_MEMORY_SCOPE_AGENT);
    }
  }

  // ---- preload W_hh fragments: A[row][k], row=lane&15, k=(lane>>4)*8+j ----
  f32x4_t wfr[2][16];
#pragma unroll
  for (int mi = 0; mi < 2; ++mi) {
    const unsigned short* wrow = Whh + (size_t)(w * HH + K0 + mi * 16 + l15) * HH + l4 * 8;
#pragma unroll
    for (int kt = 0; kt < 16; ++kt)
      wfr[mi][kt] = *(const f32x4_t*)(wrow + kt * 32);
  }
#pragma unroll
  for (int mi = 0; mi < 2; ++mi)
#pragma unroll
    for (int kt = 0; kt < 16; ++kt)
      asm volatile("" : "+v"(wfr[mi][kt]));

  float c_reg = 0.f;                      // lives on wave 3 lanes 0..31
  const f32x4_t z4 = {0.f, 0.f, 0.f, 0.f};

  // distributed-activation lane mapping (all 4 waves): lanes l15<8, 1 transc each
  const bool act_lane = (l15 < 8);
  const int r_sel = l15 & 3;
  const int jj = ((l15 >> 2) << 4) + (l4 << 2) + r_sel;
  const unsigned short* xgp = xg + (size_t)(b << 10) * GG + w * HH + K0 + jj;
  float xcur = 0.f;
  if (act_lane) xcur = bf2f(xgp[0]);

  // poller roles: tid<64 -> 2 u64 words; 64<=tid<192 -> 1; wave 3 -> none
  const unsigned long long msk = 0xFFFF0000FFFF0000ull;

  for (int t = 0; t < LL; ++t) {
    const unsigned long long tg   = (unsigned long long)(unsigned int)t;
    const unsigned long long expv = (tg << 16) | (tg << 48);
    unsigned long long* base = (unsigned long long*)(tbuf + (((t & 1) * BB + b) << 9));

    if (tid < 192) {
      const int nq  = (tid < 64) ? 2 : 1;
      const int q0  = (tid < 64) ? (tid * 2) : (tid + 64);
#pragma unroll
      for (int k = 0; k < 2; ++k) {
        if (k >= nq) break;
        unsigned long long* src = base + q0 + k;
        unsigned long long v = 0;
        unsigned int guard = 0;
        bool got = false;
        for (;;) {
          if (mode_local) {
            for (int it = 0; it < 16; ++it) {
              unsigned long long lv;
              asm volatile("global_load_dwordx2 %0, %1, off sc0\n\ts_waitcnt vmcnt(0)"
                           : "=v"(lv) : "v"(src));
              if ((lv & msk) == expv) { v = lv; got = true; break; }
            }
            if (got) break;
          }
          v = __hip_atomic_load(src, __ATOMIC_RELAXED, __HIP_MEMORY_SCOPE_AGENT);
          if ((v & msk) == expv) break;
          if (++guard > (1u << 18)) break;   // failsafe: wrong-answer beats a hang
        }
        const int q = q0 + k;
        ushort2 hv2; hv2.x = (unsigned short)v; hv2.y = (unsigned short)(v >> 32);
        ((ushort2*)h_lds)[q] = hv2;
      }
    }
    __syncthreads();   // barrier #1: h staged

    // ---- issue next step's xg scalar load (act lanes; hides under MFMA) ----
    unsigned short xnx = 0;
    if (act_lane && (t + 1 < LL)) xnx = xgp[(size_t)(t + 1) * GG];

    // ---- gates: 4 independent MFMA chains of 8 ----
    f32x4_t a0a = z4, a0b = z4, a1a = z4, a1b = z4;
#pragma unroll
    for (int kt = 0; kt < 8; ++kt) {
      bf16x8_t hva = *(const bf16x8_t*)(h_lds + kt * 32 + l4 * 8);
      bf16x8_t hvb = *(const bf16x8_t*)(h_lds + (kt + 8) * 32 + l4 * 8);
      a0a = MFMA_BF16(__builtin_bit_cast(bf16x8_t, wfr[0][kt]),     hva, a0a);
      a1a = MFMA_BF16(__builtin_bit_cast(bf16x8_t, wfr[1][kt]),     hva, a1a);
      a0b = MFMA_BF16(__builtin_bit_cast(bf16x8_t, wfr[0][kt + 8]), hvb, a0b);
      a1b = MFMA_BF16(__builtin_bit_cast(bf16x8_t, wfr[1][kt + 8]), hvb, a1b);
    }

    // ---- distributed activation: one transcendental per lane ----
    if (act_lane) {
      f32x4_t s = (l15 >= 4) ? (a1a + a1b) : (a0a + a0b);
      float e01 = (r_sel & 1) ? s[1] : s[0];
      float e23 = (r_sel & 1) ? s[3] : s[2];
      float raw = ((r_sel & 2) ? e23 : e01) + xcur;
      gl[w][jj] = (w == 2) ? tanhf_fast(raw) : sigmoidf_fast(raw);
    }
    __syncthreads();   // barrier #2: gates ready

    // ---- tail on WAVE 3 (never polls; its store acks drain off-path) ----
    if (tid >= 192 && tid < 224) {
      const int e = tid - 192;
      float gi = gl[0][e], gf = gl[1][e], gc = gl[2][e], go = gl[3][e];
      c_reg = gf * c_reg + gi * gc;
      float h = go * tanhf_fast(c_reg);
      unsigned int word = ((unsigned int)(t + 1) << 16) | (unsigned int)f2bf(h);
      unsigned int* dst = tbuf + ((((t + 1) & 1) * BB + b) << 9) + K0 + e;
      *(volatile unsigned int*)dst = word;                                    // local L2
      __hip_atomic_store(dst, word, __ATOMIC_RELAXED, __HIP_MEMORY_SCOPE_AGENT); // MALL
      h_all[(size_t)((b << 10) + t) * HH + K0 + e] = h;
    }

    if (act_lane) xcur = bf2f(xnx);
  }
}

// ---------------- g = argmax(logits) as float ----------------
__global__ __launch_bounds__(256) void k_gsel(const float* __restrict__ h, const float* __restrict__ Wlin,
                                              const float* __restrict__ blin, float* __restrict__ g) {
  const int lane = threadIdx.x & 63, w = threadIdx.x >> 6;
  const int idx = blockIdx.x * 4 + w;
  const float4* hp = (const float4*)(h + (size_t)idx * HH + lane * 8);
  const float4* w0 = (const float4*)(Wlin + lane * 8);
  const float4* w1 = (const float4*)(Wlin + HH + lane * 8);
  float4 h0 = hp[0], h1 = hp[1];
  float4 a0 = w0[0], a1 = w0[1], c0 = w1[0], c1 = w1[1];
  float s0 = h0.x*a0.x + h0.y*a0.y + h0.z*a0.z + h0.w*a0.w
           + h1.x*a1.x + h1.y*a1.y + h1.z*a1.z + h1.w*a1.w;
  float s1 = h0.x*c0.x + h0.y*c0.y + h0.z*c0.z + h0.w*c0.w
           + h1.x*c1.x + h1.y*c1.y + h1.z*c1.z + h1.w*c1.w;
#pragma unroll
  for (int off = 32; off > 0; off >>= 1) {
    s0 += __shfl_xor(s0, off);
    s1 += __shfl_xor(s1, off);
  }
  if (lane == 0) g[idx] = (s1 + blin[1] > s0 + blin[0]) ? 1.f : 0.f;
}

// ---------------- scan phase A: per-(b,seg,k) partial sums of g*h ----------------
__global__ __launch_bounds__(256) void k_scan_a(const float* __restrict__ h, const float* __restrict__ g,
                                                float* __restrict__ part) {
  const int bid = blockIdx.x;
  const int b = bid >> 4, seg = (bid >> 1) & 7, kc = bid & 1;
  const int k = kc * 256 + threadIdx.x;
  __shared__ float gs[128];
  if (threadIdx.x < 128) gs[threadIdx.x] = g[b * LL + seg * 128 + threadIdx.x];
  __syncthreads();
  const float* hp = h + ((size_t)(b * LL + seg * 128)) * HH + k;
  float sum = 0.f;
#pragma unroll 4
  for (int l = 0; l < 128; ++l) sum += gs[l] * hp[(size_t)l * HH];
  part[(b * 8 + seg) * HH + k] = sum;
}

// ---------------- scan phase B: emit 2h + fa*S_excl + ba*(S_tot - S_incl) ----------------
__global__ __launch_bounds__(256) void k_scan_b(float* __restrict__ h, const float* __restrict__ g,
                                                const float* __restrict__ part,
                                                const float* __restrict__ fwd, const float* __restrict__ bwd) {
  const int bid = blockIdx.x;
  const int b = bid >> 4, seg = (bid >> 1) & 7, kc = bid & 1;
  const int k = kc * 256 + threadIdx.x;
  __shared__ float gs[128];
  if (threadIdx.x < 128) gs[threadIdx.x] = g[b * LL + seg * 128 + threadIdx.x];
  __syncthreads();
  float base = 0.f, total = 0.f;
#pragma unroll
  for (int s = 0; s < 8; ++s) {
    float v = part[(b * 8 + s) * HH + k];
    total += v;
    if (s < seg) base += v;
  }
  const float fa = fwd[k], ba = bwd[k];
  float run = base;
  float* hp = h + ((size_t)(b * LL + seg * 128)) * HH + k;
  for (int l = 0; l < 128; ++l) {
    float hv = hp[(size_t)l * HH];
    float term = gs[l] * hv;
    hp[(size_t)l * HH] = 2.f * hv + fa * run + ba * (total - run - term);
    run += term;
  }
}

extern "C" void kernel_launch(void* const* d_in, const int* in_sizes, int n_in,
                              void* d_out, int out_size, void* d_ws, size_t ws_size,
                              hipStream_t stream) {
  if (ws_size < WS_NEED) return;
  const float* x    = (const float*)d_in[0];
  const float* Wih  = (const float*)d_in[1];
  const float* Whh  = (const float*)d_in[2];
  const float* b_ih = (const float*)d_in[3];
  const float* b_hh = (const float*)d_in[4];
  const float* Wlin = (const float*)d_in[5];
  const float* blin = (const float*)d_in[6];
  const float* fwd  = (const float*)d_in[7];
  const float* bwd  = (const float*)d_in[8];
  char* ws = (char*)d_ws;
  unsigned short* xbf   = (unsigned short*)(ws + XBF_OFF);
  unsigned short* wihbf = (unsigned short*)(ws + WIHBF_OFF);
  unsigned short* whhbf = (unsigned short*)(ws + WHHBF_OFF);
  unsigned short* xgbf  = (unsigned short*)(ws + XGBF_OFF);
  float*          garr  = (float*)(ws + GARR_OFF);
  float*          part  = (float*)(ws + PART_OFF);
  unsigned int*   tbuf  = (unsigned int*)(ws + TBUF_OFF);
  unsigned int*   tabl  = (unsigned int*)(ws + TABL_OFF);
  float* out = (float*)d_out;

  // zero the XCD registration table each call (tbuf is bootstrapped in-kernel)
  (void)hipMemsetAsync(ws + TABL_OFF, 0, 256 * 4, stream);

  k_f32_to_bf16<<<2048, 256, 0, stream>>>(x,   xbf,   MM * DD / 4);
  k_f32_to_bf16<<<1024, 256, 0, stream>>>(Wih, wihbf, GG * DD / 4);
  k_f32_to_bf16<<<256,  256, 0, stream>>>(Whh, whhbf, GG * HH / 4);
  k_gemm_xg<<<(MM / 128) * (GG / 128), 256, 0, stream>>>(xbf, wihbf, b_ih, b_hh, xgbf);
  k_lstm<<<256, 256, 0, stream>>>(whhbf, xgbf, out, tbuf, tabl);
  k_gsel<<<MM / 4, 256, 0, stream>>>(out, Wlin, blin, garr);
  k_scan_a<<<256, 256, 0, stream>>>(out, garr, part);
  k_scan_b<<<256, 256, 0, stream>>>(out, garr, part, fwd, bwd);
}

// Round 10
// 1880.928 us; speedup vs baseline: 1.6285x; 1.6285x over previous
//
#include <hip/hip_runtime.h>
#include <stdint.h>

typedef __bf16 bf16x8_t __attribute__((ext_vector_type(8)));
typedef float  f32x4_t  __attribute__((ext_vector_type(4)));

#define MFMA_BF16(A, Bv, C) __builtin_amdgcn_mfma_f32_16x16x32_bf16((A), (Bv), (C), 0, 0, 0)

static constexpr int BB = 16;      // batch
static constexpr int LL = 1024;    // seq len
static constexpr int DD = 2048;    // input dim
static constexpr int HH = 512;     // hidden
static constexpr int GG = 4 * HH;  // 2048 gate rows
static constexpr int MM = BB * LL; // 16384

// ---- workspace layout (bytes) ----
static constexpr size_t XBF_OFF   = 0;                                    // x bf16 [MM][DD]
static constexpr size_t WIHBF_OFF = XBF_OFF   + (size_t)MM * DD * 2;      // W_ih bf16 [GG][DD]
static constexpr size_t WHHBF_OFF = WIHBF_OFF + (size_t)GG * DD * 2;      // W_hh bf16 [GG][HH]
static constexpr size_t XGBF_OFF  = WHHBF_OFF + (size_t)GG * HH * 2;      // xg bf16 [MM][GG]
static constexpr size_t GARR_OFF  = XGBF_OFF  + (size_t)MM * GG * 2;      // g f32 [MM]
static constexpr size_t PART_OFF  = GARR_OFF  + (size_t)MM * 4;           // partials f32 [BB][8][HH]
static constexpr size_t TBUF_OFF  = PART_OFF  + (size_t)BB * 8 * HH * 4;  // tagged h u32 [2][BB][HH]
static constexpr size_t WS_NEED   = TBUF_OFF  + (size_t)2 * BB * HH * 4;  // ~145.2 MB

__device__ __forceinline__ unsigned short f2bf(float f) {
  union { float f; uint32_t u; } v; v.f = f;
  uint32_t r = v.u + 0x7FFFu + ((v.u >> 16) & 1u);   // RNE
  return (unsigned short)(r >> 16);
}
__device__ __forceinline__ float bf2f(unsigned short s) {
  union { uint32_t u; float f; } v; v.u = ((uint32_t)s) << 16;
  return v.f;
}
__device__ __forceinline__ float sigmoidf_fast(float x) { return 1.f / (1.f + __expf(-x)); }
__device__ __forceinline__ float tanhf_fast(float x) {
  float ax = fabsf(x);
  float e  = __expf(2.f * ax);            // inf ok for large ax
  float t  = 1.f - 2.f / (e + 1.f);       // -> 1 as e -> inf
  return copysignf(t, x);
}
__device__ __forceinline__ void async_cp16(const void* g, void* lds) {
  __builtin_amdgcn_global_load_lds((const __attribute__((address_space(1))) uint32_t*)g,
                                   (__attribute__((address_space(3))) uint32_t*)lds, 16, 0, 0);
}

// ---------------- fp32 -> bf16 convert (vectorized) ----------------
__global__ __launch_bounds__(256) void k_f32_to_bf16(const float* __restrict__ s,
                                                     unsigned short* __restrict__ d, int n4) {
  int i = blockIdx.x * 256 + threadIdx.x;
  int stride = gridDim.x * 256;
  for (; i < n4; i += stride) {
    float4 v = ((const float4*)s)[i];
    ushort4 o;
    o.x = f2bf(v.x); o.y = f2bf(v.y); o.z = f2bf(v.z); o.w = f2bf(v.w);
    ((ushort4*)d)[i] = o;
  }
}

// ---------------- xg = x @ W_ih^T + (b_ih + b_hh), bf16 MFMA ----------------
__global__ __launch_bounds__(256) void k_gemm_xg(const unsigned short* __restrict__ A,
                                                 const unsigned short* __restrict__ Bw,
                                                 const float* __restrict__ b_ih,
                                                 const float* __restrict__ b_hh,
                                                 unsigned short* __restrict__ C) {
  __shared__ __align__(16) unsigned short As[128 * 32];
  __shared__ __align__(16) unsigned short Bs[128 * 32];
  const int bid = blockIdx.x;
  const int bn = bid & 15, bm = bid >> 4;
  const int row0 = bm * 128, col0 = bn * 128;
  const int tid = threadIdx.x;
  const int lane = tid & 63, w = tid >> 6;
  const int wr = w >> 1, wc = w & 1;
  const int l15 = lane & 15, l4 = lane >> 4;

  const f32x4_t z4 = {0.f, 0.f, 0.f, 0.f};
  f32x4_t acc[4][4];
#pragma unroll
  for (int mi = 0; mi < 4; ++mi)
#pragma unroll
    for (int ni = 0; ni < 4; ++ni) acc[mi][ni] = z4;

  const unsigned short* ga = A  + (size_t)(row0 + (tid >> 2)) * DD + (tid & 3) * 8;
  const unsigned short* gb = Bw + (size_t)(col0 + (tid >> 2)) * DD + (tid & 3) * 8;
  unsigned short* asw = As + w * 512;
  unsigned short* bsw = Bs + w * 512;

  for (int k0 = 0; k0 < DD; k0 += 32) {
    async_cp16(ga + k0,           asw);
    async_cp16(ga + k0 + 64 * DD, asw + 2048);
    async_cp16(gb + k0,           bsw);
    async_cp16(gb + k0 + 64 * DD, bsw + 2048);
    __syncthreads();
    bf16x8_t af[4], bfr[4];
#pragma unroll
    for (int mi = 0; mi < 4; ++mi)
      af[mi] = *(const bf16x8_t*)(As + (wr * 64 + mi * 16 + l15) * 32 + l4 * 8);
#pragma unroll
    for (int ni = 0; ni < 4; ++ni)
      bfr[ni] = *(const bf16x8_t*)(Bs + (wc * 64 + ni * 16 + l15) * 32 + l4 * 8);
#pragma unroll
    for (int mi = 0; mi < 4; ++mi)
#pragma unroll
      for (int ni = 0; ni < 4; ++ni)
        acc[mi][ni] = MFMA_BF16(af[mi], bfr[ni], acc[mi][ni]);
    __syncthreads();
  }
#pragma unroll
  for (int ni = 0; ni < 4; ++ni) {
    int col = col0 + wc * 64 + ni * 16 + l15;
    float bias = b_ih[col] + b_hh[col];
#pragma unroll
    for (int mi = 0; mi < 4; ++mi) {
      int rowb = row0 + wr * 64 + mi * 16 + l4 * 4;
#pragma unroll
      for (int r = 0; r < 4; ++r)
        C[(size_t)(rowb + r) * GG + col] = f2bf(acc[mi][ni][r] + bias);
    }
  }
}

// ---------------- LSTM recurrence ----------------
// R5 structure + wave role separation (the ONLY change vs R5/R6):
//   waves 0-2 (192 thr): poll+stage h, never store -> poll is pure load RT.
//     (In R5 the tail threads lived on wave 0: their publish + h_all HBM
//      stores preceded the next poll in issue order, and vmcnt retires
//      in order, so every step's poll waited ~600-900cyc for store acks.)
//   wave 3: activation for gate o + tail (c-update, publish, h_all), never
//     polls; its xg load is issue-older than its stores, so vmcnt(2)
//     retires it without draining store acks.
// tid<64 polls 2 u64 words IN PARALLEL (both loads in flight, one check
// round) -- unlike R9's serialized two spin loops.
__global__ __launch_bounds__(256, 1) void k_lstm(const unsigned short* __restrict__ Whh,
                                                 const unsigned short* __restrict__ xg,
                                                 float* __restrict__ h_all,
                                                 unsigned int* tbuf) {
  const int bid = blockIdx.x;
  const int b  = (bid & 7) + 8 * (bid >> 7);  // same-XCD grouping heuristic
  const int wg = (bid >> 3) & 15;
  const int tid = threadIdx.x;
  const int lane = tid & 63, w = tid >> 6;    // wave w handles gate w (0=i,1=f,2=g,3=o)
  const int l15 = lane & 15, l4 = lane >> 4;
  const int K0 = wg * 32;

  __shared__ float gl[4][32];                 // activated gates
  __shared__ __align__(16) unsigned short h_lds[HH];

  // preload W_hh fragments: A[row][k], row=lane&15, k=(lane>>4)*8+j
  f32x4_t wfr[2][16];
#pragma unroll
  for (int mi = 0; mi < 2; ++mi) {
    const unsigned short* wrow = Whh + (size_t)(w * HH + K0 + mi * 16 + l15) * HH + l4 * 8;
#pragma unroll
    for (int kt = 0; kt < 16; ++kt)
      wfr[mi][kt] = *(const f32x4_t*)(wrow + kt * 32);
  }
#pragma unroll
  for (int mi = 0; mi < 2; ++mi)
#pragma unroll
    for (int kt = 0; kt < 16; ++kt)
      asm volatile("" : "+v"(wfr[mi][kt]));

  float c_reg = 0.f;                          // meaningful on wave 3, lanes 0..31
  const f32x4_t z4 = {0.f, 0.f, 0.f, 0.f};

  // distributed-activation lane mapping: lanes l15<8 each own one element
  const bool act_lane = (l15 < 8);
  const int r_sel = l15 & 3;
  const int jj = ((l15 >> 2) << 4) + (l4 << 2) + r_sel;
  const unsigned short* xgp = xg + (size_t)(b << 10) * GG + w * HH + K0 + jj;
  float xcur = 0.f;
  if (act_lane) xcur = bf2f(xgp[0]);          // xg[t=0]

  const unsigned long long msk = 0xFFFF0000FFFF0000ull;

  for (int t = 0; t < LL; ++t) {
    const unsigned long long tg   = (unsigned long long)(unsigned int)t;
    const unsigned long long expv = (tg << 16) | (tg << 48);
    unsigned long long* base = (unsigned long long*)(tbuf + (((t & 1) * BB + b) << 9));

    // ---- poll + stage (waves 0-2 only; no stores outstanding on these waves) ----
    if (tid < 64) {
      // two words, both loads in flight each round
      unsigned long long* s0p = base + 2 * tid;
      unsigned long long v0 = 0, v1 = 0;
      bool g0 = false, g1 = false;
      unsigned int guard = 0;
      for (;;) {
        unsigned long long n0 = __hip_atomic_load(s0p,     __ATOMIC_RELAXED, __HIP_MEMORY_SCOPE_AGENT);
        unsigned long long n1 = __hip_atomic_load(s0p + 1, __ATOMIC_RELAXED, __HIP_MEMORY_SCOPE_AGENT);
        if (!g0 && ((n0 & msk) == expv)) { v0 = n0; g0 = true; }
        if (!g1 && ((n1 & msk) == expv)) { v1 = n1; g1 = true; }
        if (g0 && g1) break;
        if (++guard > (1u << 20)) { if (!g0) v0 = n0; if (!g1) v1 = n1; break; }
      }
      ushort2 a; a.x = (unsigned short)v0; a.y = (unsigned short)(v0 >> 32);
      ushort2 c; c.x = (unsigned short)v1; c.y = (unsigned short)(v1 >> 32);
      ((ushort2*)h_lds)[2 * tid]     = a;
      ((ushort2*)h_lds)[2 * tid + 1] = c;
    } else if (tid < 192) {
      unsigned long long* src = base + (tid + 64);
      unsigned long long v = 0;
      unsigned int guard = 0;
      for (;;) {
        v = __hip_atomic_load(src, __ATOMIC_RELAXED, __HIP_MEMORY_SCOPE_AGENT);
        if ((v & msk) == expv) break;
        if (++guard > (1u << 20)) break;   // failsafe: wrong-answer beats a hang
      }
      ushort2 hv2; hv2.x = (unsigned short)v; hv2.y = (unsigned short)(v >> 32);
      ((ushort2*)h_lds)[tid + 64] = hv2;
    }
    __syncthreads();   // barrier #1: h staged

    // ---- issue next step's xg scalar load (act lanes; hides under MFMA) ----
    unsigned short xnx = 0;
    if (act_lane && (t + 1 < LL)) xnx = xgp[(size_t)(t + 1) * GG];

    // ---- gates: 4 independent MFMA chains of 8 ----
    f32x4_t a0a = z4, a0b = z4, a1a = z4, a1b = z4;
#pragma unroll
    for (int kt = 0; kt < 8; ++kt) {
      bf16x8_t hva = *(const bf16x8_t*)(h_lds + kt * 32 + l4 * 8);
      bf16x8_t hvb = *(const bf16x8_t*)(h_lds + (kt + 8) * 32 + l4 * 8);
      a0a = MFMA_BF16(__builtin_bit_cast(bf16x8_t, wfr[0][kt]),     hva, a0a);
      a1a = MFMA_BF16(__builtin_bit_cast(bf16x8_t, wfr[1][kt]),     hva, a1a);
      a0b = MFMA_BF16(__builtin_bit_cast(bf16x8_t, wfr[0][kt + 8]), hvb, a0b);
      a1b = MFMA_BF16(__builtin_bit_cast(bf16x8_t, wfr[1][kt + 8]), hvb, a1b);
    }

    // ---- distributed activation: one transcendental per lane ----
    if (act_lane) {
      f32x4_t s = (l15 >= 4) ? (a1a + a1b) : (a0a + a0b);
      float e01 = (r_sel & 1) ? s[1] : s[0];
      float e23 = (r_sel & 1) ? s[3] : s[2];
      float raw = ((r_sel & 2) ? e23 : e01) + xcur;
      gl[w][jj] = (w == 2) ? tanhf_fast(raw) : sigmoidf_fast(raw);
    }
    __syncthreads();   // barrier #2: gates ready

    // ---- tail on WAVE 3 (tid 192..223): never polls, store acks off-path ----
    if (tid >= 192 && tid < 224) {
      const int e = tid - 192;
      float gi = gl[0][e], gf = gl[1][e], gc = gl[2][e], go = gl[3][e];
      c_reg = gf * c_reg + gi * gc;
      float h = go * tanhf_fast(c_reg);
      unsigned int word = ((unsigned int)(t + 1) << 16) | (unsigned int)f2bf(h);
      unsigned int* dst = tbuf + ((((t + 1) & 1) * BB + b) << 9) + K0 + e;
      __hip_atomic_store(dst, word, __ATOMIC_RELAXED, __HIP_MEMORY_SCOPE_AGENT);
      h_all[(size_t)((b << 10) + t) * HH + K0 + e] = h;
    }

    // ---- consume xg[t+1] (after activation used xcur) ----
    if (act_lane) xcur = bf2f(xnx);
  }
}

// ---------------- g = argmax(logits) as float ----------------
__global__ __launch_bounds__(256) void k_gsel(const float* __restrict__ h, const float* __restrict__ Wlin,
                                              const float* __restrict__ blin, float* __restrict__ g) {
  const int lane = threadIdx.x & 63, w = threadIdx.x >> 6;
  const int idx = blockIdx.x * 4 + w;
  const float4* hp = (const float4*)(h + (size_t)idx * HH + lane * 8);
  const float4* w0 = (const float4*)(Wlin + lane * 8);
  const float4* w1 = (const float4*)(Wlin + HH + lane * 8);
  float4 h0 = hp[0], h1 = hp[1];
  float4 a0 = w0[0], a1 = w0[1], c0 = w1[0], c1 = w1[1];
  float s0 = h0.x*a0.x + h0.y*a0.y + h0.z*a0.z + h0.w*a0.w
           + h1.x*a1.x + h1.y*a1.y + h1.z*a1.z + h1.w*a1.w;
  float s1 = h0.x*c0.x + h0.y*c0.y + h0.z*c0.z + h0.w*c0.w
           + h1.x*c1.x + h1.y*c1.y + h1.z*c1.z + h1.w*c1.w;
#pragma unroll
  for (int off = 32; off > 0; off >>= 1) {
    s0 += __shfl_xor(s0, off);
    s1 += __shfl_xor(s1, off);
  }
  if (lane == 0) g[idx] = (s1 + blin[1] > s0 + blin[0]) ? 1.f : 0.f;
}

// ---------------- scan phase A: per-(b,seg,k) partial sums of g*h ----------------
__global__ __launch_bounds__(256) void k_scan_a(const float* __restrict__ h, const float* __restrict__ g,
                                                float* __restrict__ part) {
  const int bid = blockIdx.x;
  const int b = bid >> 4, seg = (bid >> 1) & 7, kc = bid & 1;
  const int k = kc * 256 + threadIdx.x;
  __shared__ float gs[128];
  if (threadIdx.x < 128) gs[threadIdx.x] = g[b * LL + seg * 128 + threadIdx.x];
  __syncthreads();
  const float* hp = h + ((size_t)(b * LL + seg * 128)) * HH + k;
  float sum = 0.f;
#pragma unroll 4
  for (int l = 0; l < 128; ++l) sum += gs[l] * hp[(size_t)l * HH];
  part[(b * 8 + seg) * HH + k] = sum;
}

// ---------------- scan phase B: emit 2h + fa*S_excl + ba*(S_tot - S_incl) ----------------
__global__ __launch_bounds__(256) void k_scan_b(float* __restrict__ h, const float* __restrict__ g,
                                                const float* __restrict__ part,
                                                const float* __restrict__ fwd, const float* __restrict__ bwd) {
  const int bid = blockIdx.x;
  const int b = bid >> 4, seg = (bid >> 1) & 7, kc = bid & 1;
  const int k = kc * 256 + threadIdx.x;
  __shared__ float gs[128];
  if (threadIdx.x < 128) gs[threadIdx.x] = g[b * LL + seg * 128 + threadIdx.x];
  __syncthreads();
  float base = 0.f, total = 0.f;
#pragma unroll
  for (int s = 0; s < 8; ++s) {
    float v = part[(b * 8 + s) * HH + k];
    total += v;
    if (s < seg) base += v;
  }
  const float fa = fwd[k], ba = bwd[k];
  float run = base;
  float* hp = h + ((size_t)(b * LL + seg * 128)) * HH + k;
  for (int l = 0; l < 128; ++l) {
    float hv = hp[(size_t)l * HH];
    float term = gs[l] * hv;
    hp[(size_t)l * HH] = 2.f * hv + fa * run + ba * (total - run - term);
    run += term;
  }
}

extern "C" void kernel_launch(void* const* d_in, const int* in_sizes, int n_in,
                              void* d_out, int out_size, void* d_ws, size_t ws_size,
                              hipStream_t stream) {
  if (ws_size < WS_NEED) return;
  const float* x    = (const float*)d_in[0];
  const float* Wih  = (const float*)d_in[1];
  const float* Whh  = (const float*)d_in[2];
  const float* b_ih = (const float*)d_in[3];
  const float* b_hh = (const float*)d_in[4];
  const float* Wlin = (const float*)d_in[5];
  const float* blin = (const float*)d_in[6];
  const float* fwd  = (const float*)d_in[7];
  const float* bwd  = (const float*)d_in[8];
  char* ws = (char*)d_ws;
  unsigned short* xbf   = (unsigned short*)(ws + XBF_OFF);
  unsigned short* wihbf = (unsigned short*)(ws + WIHBF_OFF);
  unsigned short* whhbf = (unsigned short*)(ws + WHHBF_OFF);
  unsigned short* xgbf  = (unsigned short*)(ws + XGBF_OFF);
  float*          garr  = (float*)(ws + GARR_OFF);
  float*          part  = (float*)(ws + PART_OFF);
  unsigned int*   tbuf  = (unsigned int*)(ws + TBUF_OFF);
  float* out = (float*)d_out;

  // zero tagged h buffer: tag 0 == valid h[-1] = 0 (deterministic across graph replays)
  (void)hipMemsetAsync(ws + TBUF_OFF, 0, (size_t)2 * BB * HH * 4, stream);

  k_f32_to_bf16<<<2048, 256, 0, stream>>>(x,   xbf,   MM * DD / 4);
  k_f32_to_bf16<<<1024, 256, 0, stream>>>(Wih, wihbf, GG * DD / 4);
  k_f32_to_bf16<<<256,  256, 0, stream>>>(Whh, whhbf, GG * HH / 4);
  k_gemm_xg<<<(MM / 128) * (GG / 128), 256, 0, stream>>>(xbf, wihbf, b_ih, b_hh, xgbf);
  k_lstm<<<256, 256, 0, stream>>>(whhbf, xgbf, out, tbuf);
  k_gsel<<<MM / 4, 256, 0, stream>>>(out, Wlin, blin, garr);
  k_scan_a<<<256, 256, 0, stream>>>(out, garr, part);
  k_scan_b<<<256, 256, 0, stream>>>(out, garr, part, fwd, bwd);
}